// Round 7
// baseline (83.848 us; speedup 1.0000x reference)
//
#include <hip/hip_runtime.h>

#define NB 16
#define CIN 3
#define HH 64
#define WW 64
#define COUT 32
#define NT 32
#define EPSF 1e-8f

// spk_rec elements: 16*32*32*64*64 = 67108864
#define SPK_ELEMS 67108864
#define DENOM_SPREAD 2097152.0f   // 16*32*64*64
#define DENOM_MEAN 67108864.0f
#define NBLOCKS 2048              // 4 blocks per (b, co)

template <int USE_PART>
__global__ __launch_bounds__(256) void spiking_main_kernel(
    const float* __restrict__ x, const float* __restrict__ w,
    const float* __restrict__ bias, float* __restrict__ out,
    int* __restrict__ cnt)
{
    __shared__ int s_cnt[NT];
    const int tid = threadIdx.x;
    if (tid < NT) s_cnt[tid] = 0;
    __syncthreads();

    // grid: 2048 blocks. 4 blocks per (b,co); 256 threads * 4 px = 1024 px/block
    const int bc    = blockIdx.x >> 2;       // 0..511
    const int chunk = blockIdx.x & 3;        // 0..3
    const int b  = bc >> 5;                  // 0..15
    const int co = bc & 31;                  // 0..31
    const int p0 = chunk * 1024 + tid * 4;   // pixel index, multiple of 4
    const int h  = p0 >> 6;
    const int w0 = p0 & 63;                  // 4 consecutive cols, same row

    // weights
    const float* wc = w + co * 27;
    float wreg[27];
    #pragma unroll
    for (int k = 0; k < 27; ++k) wreg[k] = wc[k];

    // norm = sum(w*w) replicating numpy pairwise_sum for n=27:
    //   r[0..7]=a[0..7]; r[j]+=a[8+j]; r[j]+=a[16+j];
    //   res=((r0+r1)+(r2+r3))+((r4+r5)+(r6+r7)); res+=a[24]; res+=a[25]; res+=a[26];
    float w2[27];
    #pragma unroll
    for (int k = 0; k < 27; ++k) w2[k] = __fmul_rn(wreg[k], wreg[k]);
    float r[8];
    #pragma unroll
    for (int j = 0; j < 8; ++j) r[j] = w2[j];
    #pragma unroll
    for (int j = 0; j < 8; ++j) r[j] = __fadd_rn(r[j], w2[8 + j]);
    #pragma unroll
    for (int j = 0; j < 8; ++j) r[j] = __fadd_rn(r[j], w2[16 + j]);
    float norm = __fadd_rn(
        __fadd_rn(__fadd_rn(r[0], r[1]), __fadd_rn(r[2], r[3])),
        __fadd_rn(__fadd_rn(r[4], r[5]), __fadd_rn(r[6], r[7])));
    norm = __fadd_rn(norm, w2[24]);
    norm = __fadd_rn(norm, w2[25]);
    norm = __fadd_rn(norm, w2[26]);

    const float inv_norm = __fdiv_rn(1.0f, __fadd_rn(norm, EPSF));
    const float bv = bias[co];

    // conv for 4 consecutive pixels (row h, cols w0..w0+3), padding=1.
    // Strict per-pixel accumulation order (ci, kh, kw); rounded mul then add
    // (NO fma) to match the numpy reference. Scalar loads — EXACT Round-2
    // passing form (float4+shuffle variant failed correctness; reverted).
    float c[4] = {0.f, 0.f, 0.f, 0.f};
    const float* xb = x + b * (CIN * HH * WW);
    #pragma unroll
    for (int ci = 0; ci < CIN; ++ci) {
        #pragma unroll
        for (int kh = 0; kh < 3; ++kh) {
            const int hr = h + kh - 1;
            if (hr < 0 || hr >= HH) continue;
            const float* xrow = xb + ci * HH * WW + hr * WW;
            float xv[6];
            #pragma unroll
            for (int j = 0; j < 6; ++j) {
                const int col = w0 + j - 1;
                xv[j] = (col >= 0 && col < WW) ? xrow[col] : 0.0f;
            }
            #pragma unroll
            for (int kw = 0; kw < 3; ++kw) {
                const float wv = wreg[ci * 9 + kh * 3 + kw];
                #pragma unroll
                for (int i = 0; i < 4; ++i) {
                    c[i] = __fadd_rn(c[i], __fmul_rn(xv[i + kw], wv));
                }
            }
        }
    }

    // 32-step threshold scan; spk_rec[t] = 1.0 at first t with mem*inv - b > 0
    float mem[4] = {0.f, 0.f, 0.f, 0.f};
    int tfirst[4] = {-1, -1, -1, -1};
    float* obase = out + (size_t)bc * (NT * 4096) + p0;

    #pragma unroll
    for (int t = 0; t < NT; ++t) {
        float vv[4];
        #pragma unroll
        for (int i = 0; i < 4; ++i) {
            mem[i] = __fadd_rn(mem[i], c[i]);              // replicate np.cumsum
            const float mthr = __fsub_rn(__fmul_rn(mem[i], inv_norm), bv);
            const bool spk = (tfirst[i] < 0) && (mthr > 0.0f);
            vv[i] = spk ? 1.0f : 0.0f;
            if (spk) tfirst[i] = t;
        }
        float4 v = make_float4(vv[0], vv[1], vv[2], vv[3]);
        *reinterpret_cast<float4*>(obase + t * 4096) = v;
    }

    #pragma unroll
    for (int i = 0; i < 4; ++i) {
        if (tfirst[i] >= 0) atomicAdd(&s_cnt[tfirst[i]], 1);
    }
    __syncthreads();
    if (USE_PART) {
        // per-block histogram slot, written unconditionally -> no init needed
        if (tid < NT) cnt[blockIdx.x * NT + tid] = s_cnt[tid];
    } else {
        if (tid < NT) atomicAdd(&cnt[tid], s_cnt[tid]);
    }
}

__global__ void init_ws_kernel(int* cnt) {
    if (threadIdx.x < NT) cnt[threadIdx.x] = 0;
}

template <int USE_PART>
__global__ __launch_bounds__(256) void finalize_kernel(
    const int* __restrict__ part, float* __restrict__ out)
{
    __shared__ int s[256];
    const int t = threadIdx.x & 31;
    const int g = threadIdx.x >> 5;
    int sum = 0;
    if (USE_PART) {
        for (int k = g; k < NBLOCKS; k += 8) sum += part[k * NT + t];
    } else {
        if (g == 0) sum = part[t];
    }
    s[threadIdx.x] = sum;
    __syncthreads();
    if (threadIdx.x == 0) {
        int total = 0, mx = 0;
        for (int t2 = 0; t2 < NT; ++t2) {
            int v = 0;
            #pragma unroll
            for (int g2 = 0; g2 < 8; ++g2) v += s[g2 * NT + t2];
            total += v;
            if (v > mx) mx = v;
        }
        out[SPK_ELEMS]     = 0.5f * ((float)total / DENOM_MEAN);
        out[SPK_ELEMS + 1] = (float)mx / DENOM_SPREAD;
    }
}

extern "C" void kernel_launch(void* const* d_in, const int* in_sizes, int n_in,
                              void* d_out, int out_size, void* d_ws, size_t ws_size,
                              hipStream_t stream) {
    const float* x    = (const float*)d_in[0];
    const float* w    = (const float*)d_in[1];
    const float* bias = (const float*)d_in[2];
    // d_in[3] = sigma: unused in forward pass
    float* out = (float*)d_out;
    int* cnt   = (int*)d_ws;

    if (ws_size >= (size_t)NBLOCKS * NT * sizeof(int)) {
        // primary path: per-block partial histograms, no init, no global atomics
        spiking_main_kernel<1><<<NBLOCKS, 256, 0, stream>>>(x, w, bias, out, cnt);
        finalize_kernel<1><<<1, 256, 0, stream>>>(cnt, out);
    } else {
        init_ws_kernel<<<1, 32, 0, stream>>>(cnt);
        spiking_main_kernel<0><<<NBLOCKS, 256, 0, stream>>>(x, w, bias, out, cnt);
        finalize_kernel<0><<<1, 256, 0, stream>>>(cnt, out);
    }
}

// Round 8
// 51.954 us; speedup vs baseline: 1.6139x; 1.6139x over previous
//
#include <hip/hip_runtime.h>

#define NB 16
#define CIN 3
#define HH 64
#define WW 64
#define COUT 32
#define NT 32
#define EPSF 1e-8f

// spk_rec elements: 16*32*32*64*64 = 67108864
#define SPK_ELEMS 67108864
#define DENOM_SPREAD 2097152.0f   // 16*32*64*64
#define DENOM_MEAN 67108864.0f
#define NBLOCKS 2048              // 4 blocks per (b, co)

template <int USE_PART>
__global__ __launch_bounds__(256) void spiking_main_kernel(
    const float* __restrict__ x, const float* __restrict__ w,
    const float* __restrict__ bias, float* __restrict__ out,
    int* __restrict__ cnt)
{
    __shared__ int s_cnt[NT];
    const int tid = threadIdx.x;
    if (tid < NT) s_cnt[tid] = 0;
    __syncthreads();

    // grid: 2048 blocks. 4 blocks per (b,co); 256 threads * 4 px = 1024 px/block
    const int bc    = blockIdx.x >> 2;       // 0..511
    const int chunk = blockIdx.x & 3;        // 0..3
    const int b  = bc >> 5;                  // 0..15
    const int co = bc & 31;                  // 0..31
    const int p0 = chunk * 1024 + tid * 4;   // pixel index, multiple of 4
    const int h  = p0 >> 6;
    const int w0 = p0 & 63;                  // 4 consecutive cols, same row

    // weights
    const float* wc = w + co * 27;
    float wreg[27];
    #pragma unroll
    for (int k = 0; k < 27; ++k) wreg[k] = wc[k];

    // norm = sum(w*w) replicating numpy pairwise_sum for n=27:
    //   r[0..7]=a[0..7]; r[j]+=a[8+j]; r[j]+=a[16+j];
    //   res=((r0+r1)+(r2+r3))+((r4+r5)+(r6+r7)); res+=a[24]; res+=a[25]; res+=a[26];
    float w2[27];
    #pragma unroll
    for (int k = 0; k < 27; ++k) w2[k] = __fmul_rn(wreg[k], wreg[k]);
    float r[8];
    #pragma unroll
    for (int j = 0; j < 8; ++j) r[j] = w2[j];
    #pragma unroll
    for (int j = 0; j < 8; ++j) r[j] = __fadd_rn(r[j], w2[8 + j]);
    #pragma unroll
    for (int j = 0; j < 8; ++j) r[j] = __fadd_rn(r[j], w2[16 + j]);
    float norm = __fadd_rn(
        __fadd_rn(__fadd_rn(r[0], r[1]), __fadd_rn(r[2], r[3])),
        __fadd_rn(__fadd_rn(r[4], r[5]), __fadd_rn(r[6], r[7])));
    norm = __fadd_rn(norm, w2[24]);
    norm = __fadd_rn(norm, w2[25]);
    norm = __fadd_rn(norm, w2[26]);

    const float inv_norm = __fdiv_rn(1.0f, __fadd_rn(norm, EPSF));
    const float bv = bias[co];

    // conv for 4 consecutive pixels (row h, cols w0..w0+3), padding=1.
    // Strict per-pixel accumulation order (ci, kh, kw); rounded mul then add
    // (NO fma) to match the numpy reference. Scalar loads — proven Round-2 form.
    float c[4] = {0.f, 0.f, 0.f, 0.f};
    const float* xb = x + b * (CIN * HH * WW);
    #pragma unroll
    for (int ci = 0; ci < CIN; ++ci) {
        #pragma unroll
        for (int kh = 0; kh < 3; ++kh) {
            const int hr = h + kh - 1;
            if (hr < 0 || hr >= HH) continue;
            const float* xrow = xb + ci * HH * WW + hr * WW;
            float xv[6];
            #pragma unroll
            for (int j = 0; j < 6; ++j) {
                const int col = w0 + j - 1;
                xv[j] = (col >= 0 && col < WW) ? xrow[col] : 0.0f;
            }
            #pragma unroll
            for (int kw = 0; kw < 3; ++kw) {
                const float wv = wreg[ci * 9 + kh * 3 + kw];
                #pragma unroll
                for (int i = 0; i < 4; ++i) {
                    c[i] = __fadd_rn(c[i], __fmul_rn(xv[i + kw], wv));
                }
            }
        }
    }

    // 32-step threshold scan; spk_rec[t] = 1.0 at first t with mem*inv - b > 0
    float mem[4] = {0.f, 0.f, 0.f, 0.f};
    int tfirst[4] = {-1, -1, -1, -1};
    float* obase = out + (size_t)bc * (NT * 4096) + p0;

    #pragma unroll
    for (int t = 0; t < NT; ++t) {
        float vv[4];
        #pragma unroll
        for (int i = 0; i < 4; ++i) {
            mem[i] = __fadd_rn(mem[i], c[i]);              // replicate np.cumsum
            const float mthr = __fsub_rn(__fmul_rn(mem[i], inv_norm), bv);
            const bool spk = (tfirst[i] < 0) && (mthr > 0.0f);
            vv[i] = spk ? 1.0f : 0.0f;
            if (spk) tfirst[i] = t;
        }
        float4 v = make_float4(vv[0], vv[1], vv[2], vv[3]);
        *reinterpret_cast<float4*>(obase + t * 4096) = v;
    }

    #pragma unroll
    for (int i = 0; i < 4; ++i) {
        if (tfirst[i] >= 0) atomicAdd(&s_cnt[tfirst[i]], 1);
    }
    __syncthreads();
    if (USE_PART) {
        // per-block histogram slot, written unconditionally -> no init needed
        if (tid < NT) cnt[blockIdx.x * NT + tid] = s_cnt[tid];
    } else {
        if (tid < NT) atomicAdd(&cnt[tid], s_cnt[tid]);
    }
}

__global__ void init_ws_kernel(int* cnt) {
    if (threadIdx.x < NT) cnt[threadIdx.x] = 0;
}

// Parallel finalize for the partials path: 1024 threads stream 2048*32 ints
// as coalesced int4 (idx = i*1024 + j). For int4 index idx, its 4 elements
// fall in bins 4*(idx&7)+{0..3}, and idx&7 == j&7 is CONSTANT per thread ->
// 4 register accumulators, no dependent-latency chain (Round 7's rolled
// strided-scalar finalize was a ~25 us serial latency chain).
__global__ __launch_bounds__(1024) void finalize_part_kernel(
    const int* __restrict__ part, float* __restrict__ out)
{
    __shared__ int s_bins[NT];
    const int j = threadIdx.x;
    if (j < NT) s_bins[j] = 0;
    __syncthreads();

    const int4* p4 = reinterpret_cast<const int4*>(part);
    int a0 = 0, a1 = 0, a2 = 0, a3 = 0;
    #pragma unroll
    for (int i = 0; i < 16; ++i) {
        const int4 v = p4[i * 1024 + j];
        a0 += v.x; a1 += v.y; a2 += v.z; a3 += v.w;
    }
    const int g4 = (j & 7) * 4;
    atomicAdd(&s_bins[g4 + 0], a0);
    atomicAdd(&s_bins[g4 + 1], a1);
    atomicAdd(&s_bins[g4 + 2], a2);
    atomicAdd(&s_bins[g4 + 3], a3);
    __syncthreads();

    if (j == 0) {
        int total = 0, mx = 0;
        for (int t = 0; t < NT; ++t) {
            const int v = s_bins[t];
            total += v;
            if (v > mx) mx = v;
        }
        out[SPK_ELEMS]     = 0.5f * ((float)total / DENOM_MEAN);
        out[SPK_ELEMS + 1] = (float)mx / DENOM_SPREAD;
    }
}

// Fallback finalize for the atomic path (cnt[0..31] already final)
__global__ void finalize_atomic_kernel(const int* __restrict__ cnt, float* __restrict__ out)
{
    int total = 0, mx = 0;
    for (int t = 0; t < NT; ++t) {
        const int v = cnt[t];
        total += v;
        if (v > mx) mx = v;
    }
    out[SPK_ELEMS]     = 0.5f * ((float)total / DENOM_MEAN);
    out[SPK_ELEMS + 1] = (float)mx / DENOM_SPREAD;
}

extern "C" void kernel_launch(void* const* d_in, const int* in_sizes, int n_in,
                              void* d_out, int out_size, void* d_ws, size_t ws_size,
                              hipStream_t stream) {
    const float* x    = (const float*)d_in[0];
    const float* w    = (const float*)d_in[1];
    const float* bias = (const float*)d_in[2];
    // d_in[3] = sigma: unused in forward pass
    float* out = (float*)d_out;
    int* cnt   = (int*)d_ws;

    if (ws_size >= (size_t)NBLOCKS * NT * sizeof(int)) {
        // primary path: per-block partial histograms, no init, no global atomics
        spiking_main_kernel<1><<<NBLOCKS, 256, 0, stream>>>(x, w, bias, out, cnt);
        finalize_part_kernel<<<1, 1024, 0, stream>>>(cnt, out);
    } else {
        init_ws_kernel<<<1, 32, 0, stream>>>(cnt);
        spiking_main_kernel<0><<<NBLOCKS, 256, 0, stream>>>(x, w, bias, out, cnt);
        finalize_atomic_kernel<<<1, 1, 0, stream>>>(cnt, out);
    }
}